// Round 7
// baseline (1730.735 us; speedup 1.0000x reference)
//
#include <hip/hip_runtime.h>
#include <stdint.h>

// ---------------------------------------------------------------------------
// ThermalLatticeSampler2D — round 7: branchless Metropolis (unconditional
// dual hash, threshold-select folds dE<=0 accept), alignbit rotates, init
// fused into first sweep. R5/R6 whole-plane-in-LDS structure retained.
//
// Bit-exact jax.random (threefry2x32, partitionable mode) — validated R2-R6.
// State: int8 +-1 in d_out bytes [0,N), N=33554432 (in-place).
// After 16 sweeps: staged in-place int8->fp32 expansion fills d_out floats;
// energies -> d_out tail (512 floats).
// ---------------------------------------------------------------------------

#define BB 32
#define CC 16
#define PLANE 65536
#define NSITE (BB * CC * PLANE)        // 33554432
#define NPAIR ((BB - 1) * CC)          // 496

// Full threefry (host key schedule + pt_decide).
__host__ __device__ __forceinline__ void tf2x32(uint32_t k0, uint32_t k1,
                                                uint32_t c0, uint32_t c1,
                                                uint32_t& o0, uint32_t& o1) {
  uint32_t ks2 = k0 ^ k1 ^ 0x1BD11BDAu;
  uint32_t x0 = c0 + k0;
  uint32_t x1 = c1 + k1;
#define TF_ROT(r) { x0 += x1; x1 = (x1 << (r)) | (x1 >> (32 - (r))); x1 ^= x0; }
  TF_ROT(13) TF_ROT(15) TF_ROT(26) TF_ROT(6)
  x0 += k1;  x1 += ks2 + 1u;
  TF_ROT(17) TF_ROT(29) TF_ROT(16) TF_ROT(24)
  x0 += ks2; x1 += k0 + 2u;
  TF_ROT(13) TF_ROT(15) TF_ROT(26) TF_ROT(6)
  x0 += k0;  x1 += k1 + 3u;
  TF_ROT(17) TF_ROT(29) TF_ROT(16) TF_ROT(24)
  x0 += k1;  x1 += ks2 + 4u;
  TF_ROT(13) TF_ROT(15) TF_ROT(26) TF_ROT(6)
  x0 += ks2; x1 += k0 + 5u;
#undef TF_ROT
  o0 = x0; o1 = x1;
}

// rotl pinned to 1-op v_alignbit_b32: ((x:x) >> (32-r)) == rotl(x,r)
__device__ __forceinline__ uint32_t rotl(uint32_t x, int r) {
  return __builtin_amdgcn_alignbit(x, x, 32 - r);
}

// Device hash, c0==0, x1i = c1 + k1 precomputed. Returns (o0 ^ o1) >> 9.
__device__ __forceinline__ uint32_t tf_bits9(uint32_t k0, uint32_t k1,
                                             uint32_t ks2, uint32_t x1i) {
  uint32_t x0 = k0, x1 = x1i;
#define R4(a,b,c,d) \
  x0 += x1; x1 = rotl(x1, (a)); x1 ^= x0; \
  x0 += x1; x1 = rotl(x1, (b)); x1 ^= x0; \
  x0 += x1; x1 = rotl(x1, (c)); x1 ^= x0; \
  x0 += x1; x1 = rotl(x1, (d)); x1 ^= x0;
  R4(13,15,26,6)  x0 += k1;  x1 += ks2 + 1u;
  R4(17,29,16,24) x0 += ks2; x1 += k0 + 2u;
  R4(13,15,26,6)  x0 += k0;  x1 += k1 + 3u;
  R4(17,29,16,24) x0 += k1;  x1 += ks2 + 4u;
  R4(13,15,26,6)  x0 += ks2; x1 += k0 + 5u;
#undef R4
  return (x0 ^ x1) >> 9;
}

__device__ __forceinline__ float u01(uint32_t bits) {
  return __uint_as_float((bits >> 9) | 0x3f800000u) - 1.0f;
}

// ---- integer Metropolis thresholds: M = ceil(exp(-dE/T) * 2^23) -----------
__global__ void prep_k(const float* __restrict__ T,
                       uint32_t* __restrict__ M4, uint32_t* __restrict__ M8) {
  int b = threadIdx.x;
  if (b < BB) {
    float t = T[b];
    float th4 = (float)exp((double)((-4.0f) / t));
    float th8 = (float)exp((double)((-8.0f) / t));
    M4[b] = (uint32_t)ceil((double)th4 * 8388608.0);
    M8[b] = (uint32_t)ceil((double)th8 * 8388608.0);
  }
}

// ---- one color pass, branchless: both hashes unconditional ----------------
__device__ __forceinline__ void do_color(uint32_t* __restrict__ tile,
    int w, int lane, int lm, int lp, uint32_t vk, int color,
    uint32_t k0, uint32_t k1, uint32_t ks2, uint32_t M4b, uint32_t M8b) {
#pragma unroll 2
  for (int it = 0; it < 16; ++it) {
    int j  = w + it * 16;                     // scalar
    int rb = j << 6;                          // scalar
    int ju = ((j + 255) & 255) << 6;          // scalar
    int jd = ((j + 1) & 255) << 6;            // scalar
    int p8 = ((j + color) & 1) << 3;          // scalar: 0 or 8
    uint32_t soff = (uint32_t)((j << 8) | (p8 >> 3)); // scalar

    uint32_t cur = tile[rb + lane];
    uint32_t up  = tile[ju + lane];
    uint32_t dn  = tile[jd + lane];
    uint32_t pw  = tile[rb + lm];
    uint32_t nw  = tile[rb + lp];
    uint32_t lft = __builtin_amdgcn_alignbit(cur, pw, 24);
    uint32_t rgt = __builtin_amdgcn_alignbit(nw, cur, 8);
    // per-byte 2*(# of -1 neighbors), values 0..8, no cross-byte carry
    uint32_t kd2 = (up & 0x02020202u) + (dn & 0x02020202u)
                 + (lft & 0x02020202u) + (rgt & 0x02020202u);

    // two independent straight-line hash chains (ILP)
    uint32_t nA = tf_bits9(k0, k1, ks2, vk + soff);
    uint32_t nB = tf_bits9(k0, k1, ks2, vk + soff + 2u);

    // site A: byte p8/8
    uint32_t kdA = (kd2 >> p8) & 0xFFu;
    uint32_t sA  = (cur >> (p8 + 1)) & 1u;
    uint32_t m2A = sA ? (8u - kdA) : kdA;     // 2*(# antiparallel)
    uint32_t thA = (m2A == 2u) ? M4b : M8b;
    if (m2A >= 4u) thA = 0xFFFFFFFFu;         // dE<=0: always accept (n<2^23)
    uint32_t flip = (nA < thA) ? (0xFEu << p8) : 0u;

    // site B: byte p8/8 + 2
    uint32_t kdB = (kd2 >> (p8 + 16)) & 0xFFu;
    uint32_t sB  = (cur >> (p8 + 17)) & 1u;
    uint32_t m2B = sB ? (8u - kdB) : kdB;
    uint32_t thB = (m2B == 2u) ? M4b : M8b;
    if (m2B >= 4u) thB = 0xFFFFFFFFu;
    if (nB < thB) flip |= (0xFE0000u << p8);

    tile[rb + lane] = cur ^ flip;
  }
}

// ---- 4 sweeps on one plane, fully LDS-resident; exact energy at end -------
__global__ __launch_bounds__(1024) void sweep4_k(
    uint8_t* __restrict__ sg, const int* __restrict__ spins, int doInit,
    const uint32_t* __restrict__ M4, const uint32_t* __restrict__ M8,
    uint4 kS0, uint4 kS1, uint4 kS2, uint4 kS3,
    int tbase, const int* __restrict__ nsw, float* __restrict__ Eplane) {
  __shared__ uint32_t tile[16384];           // exactly 64 KB
  int tid = threadIdx.x;
  int bc  = blockIdx.x;
  int b   = bc >> 4;
  uint32_t bcbase = (uint32_t)bc << 16;
  uint32_t* gp = (uint32_t*)(sg + ((size_t)bc << 16));
  uint32_t M4b = M4[b], M8b = M8[b];
  int nswv = *nsw;

  if (doInit) {                              // int32 {0,1} -> packed int8 +-1
    const int4* ip = (const int4*)(spins + ((size_t)bc << 16));
    for (int i = tid; i < 16384; i += 1024) {
      int4 v = ip[i];
      tile[i] = ((uint32_t)(uint8_t)(int8_t)(2 * v.x - 1))
              | ((uint32_t)(uint8_t)(int8_t)(2 * v.y - 1) << 8)
              | ((uint32_t)(uint8_t)(int8_t)(2 * v.z - 1) << 16)
              | ((uint32_t)(uint8_t)(int8_t)(2 * v.w - 1) << 24);
    }
  } else {
    for (int i = tid; i < 4096; i += 1024)
      ((uint4*)tile)[i] = ((const uint4*)gp)[i];
  }
  __syncthreads();

  int w    = __builtin_amdgcn_readfirstlane(tid >> 6);  // wave-uniform
  int lane = tid & 63;
  int lm   = (lane + 63) & 63, lp = (lane + 1) & 63;

  uint4 keys[4] = {kS0, kS1, kS2, kS3};
#pragma unroll
  for (int ss = 0; ss < 4; ++ss) {
    if (tbase + ss < nswv) {                 // uniform
      uint32_t kA0 = keys[ss].x, kA1 = keys[ss].y;
      uint32_t kB0 = keys[ss].z, kB1 = keys[ss].w;
      uint32_t ksA = kA0 ^ kA1 ^ 0x1BD11BDAu;
      uint32_t ksB = kB0 ^ kB1 ^ 0x1BD11BDAu;
      uint32_t vkA = kA1 + bcbase + (uint32_t)(lane << 2);
      uint32_t vkB = kB1 + bcbase + (uint32_t)(lane << 2);
      do_color(tile, w, lane, lm, lp, vkA, 0, kA0, kA1, ksA, M4b, M8b);
      __syncthreads();
      do_color(tile, w, lane, lm, lp, vkB, 1, kB0, kB1, ksB, M4b, M8b);
      __syncthreads();
    }
  }

  // exact integer energy partial: sum s*(right+down) over owned words
  int acc = 0;
  for (int it = 0; it < 16; ++it) {
    int j = w + it * 16;
    uint32_t cur = tile[(j << 6) + lane];
    uint32_t nxt = tile[(j << 6) + lp];
    uint32_t dwn = tile[((((j + 1) & 255)) << 6) + lane];
    uint32_t rsh = (cur >> 8) | (nxt << 24);
    int d = __builtin_popcount((cur ^ rsh) & 0x02020202u)
          + __builtin_popcount((cur ^ dwn) & 0x02020202u);
    acc += 8 - 2 * d;
  }

  for (int i = tid; i < 4096; i += 1024)
    ((uint4*)gp)[i] = ((uint4*)tile)[i];
  __syncthreads();

  for (int off = 32; off > 0; off >>= 1) acc += __shfl_down(acc, off, 64);
  if (lane == 0) tile[w] = (uint32_t)acc;
  __syncthreads();
  if (tid == 0) {
    int tot = 0;
    for (int i = 0; i < 16; ++i) tot += (int)tile[i];
    Eplane[bc] = -(float)tot;
  }
}

// ---- PT swap decision ------------------------------------------------------
__global__ void pt_decide_k(const float* __restrict__ Eplane,
                            const float* __restrict__ T,
                            uint32_t k0, uint32_t k1, int pair_parity,
                            int* __restrict__ accf, int t,
                            const int* __restrict__ nsw) {
  int tid = threadIdx.x;
  if (tid >= NPAIR) return;
  if (t >= *nsw) { accf[tid] = 0; return; }
  int b = tid >> 4;
  float d = (1.0f / T[b] - 1.0f / T[b + 1]) * (Eplane[tid] - Eplane[tid + 16]);
  uint32_t h0, h1;
  tf2x32(k0, k1, 0u, (uint32_t)tid, h0, h1);
  float u = u01(h0 ^ h1);
  float th = (float)exp((double)d);
  accf[tid] = (u < th) && ((b & 1) == pair_parity);
}

// ---- apply accepted swaps: exchange 64KB planes ---------------------------
__global__ __launch_bounds__(256) void pt_swap8_k(uint8_t* __restrict__ s,
                                                  const int* __restrict__ accf) {
  int pc = blockIdx.x;
  if (!accf[pc]) return;
  uint4* p0 = (uint4*)(s + ((size_t)pc << 16));
  uint4* p1 = p0 + (CC * PLANE / 16);
  for (int j = threadIdx.x; j < PLANE / 16; j += 256) {
    uint4 a0 = p0[j], a1 = p1[j];
    p0[j] = a1; p1[j] = a0;
  }
}

// ---- final energies = PT(t=15) permutation of plane energies --------------
__global__ void final_eout_k(const float* __restrict__ Eplane,
                             const int* __restrict__ accf,
                             float* __restrict__ Eout) {
  int tid = threadIdx.x;
  int b = tid >> 4;
  float e = Eplane[tid];
  if (b < 31 && accf[tid])      e = Eplane[tid + 16];
  if (b > 0  && accf[tid - 16]) e = Eplane[tid - 16];
  Eout[tid] = e;
}

// ---- staged in-place int8 -> fp32 expansion (validated R3-R6) -------------
__global__ __launch_bounds__(256) void expand_k(const int8_t* __restrict__ st,
                                                float* __restrict__ out,
                                                int lo, int cnt4) {
  int i = blockIdx.x * 256 + threadIdx.x;
  if (i >= cnt4) return;
  uint32_t v = *(const uint32_t*)(st + lo + 4 * i);
  float4 o;
  o.x = (float)(int8_t)(v);
  o.y = (float)(int8_t)(v >> 8);
  o.z = (float)(int8_t)(v >> 16);
  o.w = (float)(int8_t)(v >> 24);
  ((float4*)out)[(lo >> 2) + i] = o;
}

__global__ __launch_bounds__(256) void expand_head_k(const int8_t* __restrict__ st,
                                                     float* __restrict__ out) {
  uint32_t r[8];
  int t = threadIdx.x;
  for (int u = 0; u < 8; ++u) r[u] = *(const uint32_t*)(st + t * 32 + 4 * u);
  __syncthreads();
  for (int u = 0; u < 8; ++u) {
    uint32_t v = r[u];
    float4 o;
    o.x = (float)(int8_t)(v);
    o.y = (float)(int8_t)(v >> 8);
    o.z = (float)(int8_t)(v >> 16);
    o.w = (float)(int8_t)(v >> 24);
    ((float4*)out)[t * 8 + u] = o;
  }
}

extern "C" void kernel_launch(void* const* d_in, const int* in_sizes, int n_in,
                              void* d_out, int out_size, void* d_ws, size_t ws_size,
                              hipStream_t stream) {
  (void)in_sizes; (void)n_in; (void)out_size; (void)ws_size;
  const float* T    = (const float*)d_in[0];
  const int*  spins = (const int*)d_in[1];
  const int*  nsw   = (const int*)d_in[2];

  uint8_t* buf0 = (uint8_t*)d_out;
  float*   outf = (float*)d_out;
  float*   Eout = outf + NSITE;

  float*    Eplane = (float*)d_ws;               // 512
  uint32_t* M4     = (uint32_t*)(Eplane + 512);  // 32
  uint32_t* M8     = M4 + BB;                    // 32
  int*      accf   = (int*)(M8 + BB);            // 496

  prep_k<<<1, 64, 0, stream>>>(T, M4, M8);

  for (int g = 0; g < 4; ++g) {
    uint4 kS[4];
    uint32_t k3a = 0, k3b = 0;
    for (int i = 0; i < 4; ++i) {
      int t = 4 * g + i;
      uint32_t kb0, kb1;
      tf2x32(0u, 42u, 0u, (uint32_t)t, kb0, kb1);     // fold_in(key(42), t)
      tf2x32(kb0, kb1, 0u, 0u, kS[i].x, kS[i].y);     // color-0 key
      tf2x32(kb0, kb1, 0u, 1u, kS[i].z, kS[i].w);     // color-1 key
      if (i == 3) tf2x32(kb0, kb1, 0u, 2u, k3a, k3b); // PT key
    }
    sweep4_k<<<BB * CC, 1024, 0, stream>>>(buf0, spins, (g == 0) ? 1 : 0,
                                           M4, M8,
                                           kS[0], kS[1], kS[2], kS[3],
                                           4 * g, nsw, Eplane);
    pt_decide_k<<<1, 512, 0, stream>>>(Eplane, T, k3a, k3b, g & 1,
                                       accf, 4 * g + 3, nsw);
    pt_swap8_k<<<NPAIR, 256, 0, stream>>>(buf0, accf);
  }

  final_eout_k<<<1, 512, 0, stream>>>(Eplane, accf, Eout);

  for (int lo = NSITE / 4; lo >= 8192; lo >>= 2) {
    int cnt4 = (lo * 3) / 4;
    expand_k<<<(cnt4 + 255) / 256, 256, 0, stream>>>((int8_t*)buf0, outf, lo, cnt4);
  }
  expand_head_k<<<1, 256, 0, stream>>>((int8_t*)buf0, outf);
}

// Round 8
// 1454.213 us; speedup vs baseline: 1.1902x; 1.1902x over previous
//
#include <hip/hip_runtime.h>
#include <stdint.h>

// ---------------------------------------------------------------------------
// ThermalLatticeSampler2D — round 8: R6 hot loop verbatim (branchy Metropolis,
// alignbit rotates, scalarized rows — measured best, ~roofline for 16-wide
// int VALU) + tail restructuring: inline PT decisions in swap blocks,
// single-pass expansion through d_ws (staged fallback), 10 launches total.
//
// Bit-exact jax.random (threefry2x32, partitionable mode) — validated R2-R7.
// State: int8 +-1 in d_out bytes [0,N), N=33554432 (in-place).
// ---------------------------------------------------------------------------

#define BB 32
#define CC 16
#define PLANE 65536
#define NSITE (BB * CC * PLANE)        // 33554432
#define NPAIR ((BB - 1) * CC)          // 496

// Full threefry (host key schedule + PT decisions).
__host__ __device__ __forceinline__ void tf2x32(uint32_t k0, uint32_t k1,
                                                uint32_t c0, uint32_t c1,
                                                uint32_t& o0, uint32_t& o1) {
  uint32_t ks2 = k0 ^ k1 ^ 0x1BD11BDAu;
  uint32_t x0 = c0 + k0;
  uint32_t x1 = c1 + k1;
#define TF_ROT(r) { x0 += x1; x1 = (x1 << (r)) | (x1 >> (32 - (r))); x1 ^= x0; }
  TF_ROT(13) TF_ROT(15) TF_ROT(26) TF_ROT(6)
  x0 += k1;  x1 += ks2 + 1u;
  TF_ROT(17) TF_ROT(29) TF_ROT(16) TF_ROT(24)
  x0 += ks2; x1 += k0 + 2u;
  TF_ROT(13) TF_ROT(15) TF_ROT(26) TF_ROT(6)
  x0 += k0;  x1 += k1 + 3u;
  TF_ROT(17) TF_ROT(29) TF_ROT(16) TF_ROT(24)
  x0 += k1;  x1 += ks2 + 4u;
  TF_ROT(13) TF_ROT(15) TF_ROT(26) TF_ROT(6)
  x0 += ks2; x1 += k0 + 5u;
#undef TF_ROT
  o0 = x0; o1 = x1;
}

// rotl pinned to 1-op v_alignbit_b32
__device__ __forceinline__ uint32_t rotl(uint32_t x, int r) {
  return __builtin_amdgcn_alignbit(x, x, 32 - r);
}

// Device hash, c0==0, x1i = c1 + k1 precomputed. Returns o0 ^ o1.
__device__ __forceinline__ uint32_t tf_bits(uint32_t k0, uint32_t k1,
                                            uint32_t ks2, uint32_t x1i) {
  uint32_t x0 = k0, x1 = x1i;
#define R4(a,b,c,d) \
  x0 += x1; x1 = rotl(x1, (a)); x1 ^= x0; \
  x0 += x1; x1 = rotl(x1, (b)); x1 ^= x0; \
  x0 += x1; x1 = rotl(x1, (c)); x1 ^= x0; \
  x0 += x1; x1 = rotl(x1, (d)); x1 ^= x0;
  R4(13,15,26,6)  x0 += k1;  x1 += ks2 + 1u;
  R4(17,29,16,24) x0 += ks2; x1 += k0 + 2u;
  R4(13,15,26,6)  x0 += k0;  x1 += k1 + 3u;
  R4(17,29,16,24) x0 += k1;  x1 += ks2 + 4u;
  R4(13,15,26,6)  x0 += ks2; x1 += k0 + 5u;
#undef R4
  return x0 ^ x1;
}

__device__ __forceinline__ float u01(uint32_t bits) {
  return __uint_as_float((bits >> 9) | 0x3f800000u) - 1.0f;
}

// Shared PT pair-accept decision (identical math to validated pt_decide_k).
__device__ __forceinline__ bool pt_accept(int pair, const float* Eplane,
                                          const float* T,
                                          uint32_t k0, uint32_t k1) {
  int b = pair >> 4;
  float d = (1.0f / T[b] - 1.0f / T[b + 1])
          * (Eplane[pair] - Eplane[pair + 16]);
  uint32_t h0, h1;
  tf2x32(k0, k1, 0u, (uint32_t)pair, h0, h1);
  float u = u01(h0 ^ h1);
  float th = (float)exp((double)d);
  return u < th;
}

// ---- init (int32 {0,1} -> int8 +-1) + thresholds in block 0 ---------------
__global__ __launch_bounds__(256) void init8_prep_k(
    const int* __restrict__ spins, uint8_t* __restrict__ s,
    const float* __restrict__ T,
    uint32_t* __restrict__ M4, uint32_t* __restrict__ M8) {
  int i = blockIdx.x * 256 + threadIdx.x;
  int4 v = ((const int4*)spins)[i];
  uint32_t o = ((uint32_t)(uint8_t)(int8_t)(2 * v.x - 1))
             | ((uint32_t)(uint8_t)(int8_t)(2 * v.y - 1) << 8)
             | ((uint32_t)(uint8_t)(int8_t)(2 * v.z - 1) << 16)
             | ((uint32_t)(uint8_t)(int8_t)(2 * v.w - 1) << 24);
  ((uint32_t*)s)[i] = o;
  if (blockIdx.x == 0 && threadIdx.x < BB) {
    int b = threadIdx.x;
    float t = T[b];
    float th4 = (float)exp((double)((-4.0f) / t));
    float th8 = (float)exp((double)((-8.0f) / t));
    M4[b] = (uint32_t)ceil((double)th4 * 8388608.0);
    M8[b] = (uint32_t)ceil((double)th8 * 8388608.0);
  }
}

// ---- one color pass over the plane in LDS (R6 verbatim) -------------------
__device__ __forceinline__ void do_color(uint32_t* __restrict__ tile,
    int w, int lane, int lm, int lp, uint32_t vk, int color,
    uint32_t k0, uint32_t k1, uint32_t ks2, uint32_t M4b, uint32_t M8b) {
#pragma unroll 4
  for (int it = 0; it < 16; ++it) {
    int j  = w + it * 16;                     // scalar
    int rb = j << 6;                          // scalar
    int ju = ((j + 255) & 255) << 6;          // scalar
    int jd = ((j + 1) & 255) << 6;            // scalar
    int p  = (j + color) & 1;                 // scalar
    uint32_t soff = (uint32_t)((j << 8) + p); // scalar

    uint32_t cur = tile[rb + lane];
    uint32_t up  = tile[ju + lane];
    uint32_t dn  = tile[jd + lane];
    uint32_t pw  = tile[rb + lm];
    uint32_t nw  = tile[rb + lp];
    uint32_t lft = __builtin_amdgcn_alignbit(cur, pw, 24);
    uint32_t rgt = __builtin_amdgcn_alignbit(nw, cur, 8);
    uint32_t kd2 = (up & 0x02020202u) + (dn & 0x02020202u)
                 + (lft & 0x02020202u) + (rgt & 0x02020202u);

    uint32_t flip = 0;
    {                                        // site A: byte p
      uint32_t kdi = (kd2 >> (8 * p)) & 0xFFu;
      uint32_t si  = (cur >> (8 * p + 1)) & 1u;
      uint32_t m2  = si ? (8u - kdi) : kdi;  // 2*(# antiparallel)
      bool a = true;                         // m2>=4 -> dE<=0 -> flip
      if (m2 < 4u) {
        uint32_t n = tf_bits(k0, k1, ks2, vk + soff) >> 9;
        a = n < (m2 == 2u ? M4b : M8b);
      }
      if (a) flip |= 0xFEu << (8 * p);
    }
    {                                        // site B: byte p+2
      uint32_t kdi = (kd2 >> (8 * p + 16)) & 0xFFu;
      uint32_t si  = (cur >> (8 * p + 17)) & 1u;
      uint32_t m2  = si ? (8u - kdi) : kdi;
      bool a = true;
      if (m2 < 4u) {
        uint32_t n = tf_bits(k0, k1, ks2, vk + soff + 2u) >> 9;
        a = n < (m2 == 2u ? M4b : M8b);
      }
      if (a) flip |= 0xFE0000u << (8 * p);
    }
    tile[rb + lane] = cur ^ flip;
  }
}

// ---- 4 sweeps on one plane, fully LDS-resident; exact energy at end -------
__global__ __launch_bounds__(1024) void sweep4_k(
    uint8_t* __restrict__ sg,
    const uint32_t* __restrict__ M4, const uint32_t* __restrict__ M8,
    uint4 kS0, uint4 kS1, uint4 kS2, uint4 kS3,
    int tbase, const int* __restrict__ nsw, float* __restrict__ Eplane) {
  __shared__ uint32_t tile[16384];           // exactly 64 KB
  int tid = threadIdx.x;
  int bc  = blockIdx.x;
  int b   = bc >> 4;
  uint32_t bcbase = (uint32_t)bc << 16;
  uint32_t* gp = (uint32_t*)(sg + ((size_t)bc << 16));
  uint32_t M4b = M4[b], M8b = M8[b];
  int nswv = *nsw;

  for (int i = tid; i < 4096; i += 1024)
    ((uint4*)tile)[i] = ((const uint4*)gp)[i];
  __syncthreads();

  int w    = __builtin_amdgcn_readfirstlane(tid >> 6);  // wave-uniform
  int lane = tid & 63;
  int lm   = (lane + 63) & 63, lp = (lane + 1) & 63;

  uint4 keys[4] = {kS0, kS1, kS2, kS3};
#pragma unroll
  for (int ss = 0; ss < 4; ++ss) {
    if (tbase + ss < nswv) {                 // uniform
      uint32_t kA0 = keys[ss].x, kA1 = keys[ss].y;
      uint32_t kB0 = keys[ss].z, kB1 = keys[ss].w;
      uint32_t ksA = kA0 ^ kA1 ^ 0x1BD11BDAu;
      uint32_t ksB = kB0 ^ kB1 ^ 0x1BD11BDAu;
      uint32_t vkA = kA1 + bcbase + (uint32_t)(lane << 2);
      uint32_t vkB = kB1 + bcbase + (uint32_t)(lane << 2);
      do_color(tile, w, lane, lm, lp, vkA, 0, kA0, kA1, ksA, M4b, M8b);
      __syncthreads();
      do_color(tile, w, lane, lm, lp, vkB, 1, kB0, kB1, ksB, M4b, M8b);
      __syncthreads();
    }
  }

  // exact integer energy partial: sum s*(right+down)
  int acc = 0;
  for (int it = 0; it < 16; ++it) {
    int j = w + it * 16;
    uint32_t cur = tile[(j << 6) + lane];
    uint32_t nxt = tile[(j << 6) + lp];
    uint32_t dwn = tile[((((j + 1) & 255)) << 6) + lane];
    uint32_t rsh = (cur >> 8) | (nxt << 24);
    int d = __builtin_popcount((cur ^ rsh) & 0x02020202u)
          + __builtin_popcount((cur ^ dwn) & 0x02020202u);
    acc += 8 - 2 * d;
  }

  for (int i = tid; i < 4096; i += 1024)
    ((uint4*)gp)[i] = ((uint4*)tile)[i];
  __syncthreads();

  for (int off = 32; off > 0; off >>= 1) acc += __shfl_down(acc, off, 64);
  if (lane == 0) tile[w] = (uint32_t)acc;
  __syncthreads();
  if (tid == 0) {
    int tot = 0;
    for (int i = 0; i < 16; ++i) tot += (int)tile[i];
    Eplane[bc] = -(float)tot;
  }
}

// ---- PT swap with inline decision (replaces decide+swap pair) -------------
__global__ __launch_bounds__(256) void pt_swapD_k(uint8_t* __restrict__ s,
    const float* __restrict__ Eplane, const float* __restrict__ T,
    uint32_t k0, uint32_t k1, int pair_parity, int t,
    const int* __restrict__ nsw) {
  int pc = blockIdx.x;                       // pair index, 0..495
  int b  = pc >> 4;
  if ((b & 1) != pair_parity) return;
  if (t >= *nsw) return;
  if (!pt_accept(pc, Eplane, T, k0, k1)) return;
  uint4* p0 = (uint4*)(s + ((size_t)pc << 16));
  uint4* p1 = p0 + (CC * PLANE / 16);        // plane (b+1, c)
  for (int j = threadIdx.x; j < PLANE / 16; j += 256) {
    uint4 a0 = p0[j], a1 = p1[j];
    p0[j] = a1; p1[j] = a0;
  }
}

// ---- source plane after applying t=15 swap permutation --------------------
__device__ __forceinline__ int perm_src(int pc, const float* Eplane,
                                        const float* T, uint32_t k0,
                                        uint32_t k1, int pair_parity,
                                        int t, int nswv) {
  int b = pc >> 4;
  if (t < nswv) {
    if (b < 31 && (b & 1) == pair_parity &&
        pt_accept(pc, Eplane, T, k0, k1)) return pc + 16;
    if (b > 0 && ((b - 1) & 1) == pair_parity &&
        pt_accept(pc - 16, Eplane, T, k0, k1)) return pc - 16;
  }
  return pc;
}

// ---- main path: permute final state into d_ws + write Eout ----------------
__global__ __launch_bounds__(256) void permute_out_k(
    const uint8_t* __restrict__ s, uint8_t* __restrict__ dst,
    const float* __restrict__ Eplane, const float* __restrict__ T,
    uint32_t k0, uint32_t k1, int pair_parity, int t,
    const int* __restrict__ nsw, float* __restrict__ Eout) {
  int pc = blockIdx.x;                       // 0..511
  int src = perm_src(pc, Eplane, T, k0, k1, pair_parity, t, *nsw);
  const uint4* p0 = (const uint4*)(s + ((size_t)src << 16));
  uint4*       p1 = (uint4*)(dst + ((size_t)pc << 16));
  for (int j = threadIdx.x; j < PLANE / 16; j += 256)
    p1[j] = p0[j];
  if (threadIdx.x == 0) Eout[pc] = Eplane[src];
}

// ---- main path: one-shot int8 -> fp32 expansion from d_ws -----------------
__global__ __launch_bounds__(256) void expand_full_k(
    const uint8_t* __restrict__ st, float* __restrict__ out) {
  int i = blockIdx.x * 256 + threadIdx.x;    // over NSITE/4
  uint32_t v = ((const uint32_t*)st)[i];
  float4 o;
  o.x = (float)(int8_t)(v);
  o.y = (float)(int8_t)(v >> 8);
  o.z = (float)(int8_t)(v >> 16);
  o.w = (float)(int8_t)(v >> 24);
  ((float4*)out)[i] = o;
}

// ---- fallback path: Eout with inline decisions ----------------------------
__global__ void final_eoutD_k(const float* __restrict__ Eplane,
                              const float* __restrict__ T,
                              uint32_t k0, uint32_t k1, int pair_parity,
                              int t, const int* __restrict__ nsw,
                              float* __restrict__ Eout) {
  int pc = threadIdx.x;                      // 512
  int src = perm_src(pc, Eplane, T, k0, k1, pair_parity, t, *nsw);
  Eout[pc] = Eplane[src];
}

// ---- fallback path: staged in-place expansion (validated R3-R7) -----------
__global__ __launch_bounds__(256) void expand_k(const int8_t* __restrict__ st,
                                                float* __restrict__ out,
                                                int lo, int cnt4) {
  int i = blockIdx.x * 256 + threadIdx.x;
  if (i >= cnt4) return;
  uint32_t v = *(const uint32_t*)(st + lo + 4 * i);
  float4 o;
  o.x = (float)(int8_t)(v);
  o.y = (float)(int8_t)(v >> 8);
  o.z = (float)(int8_t)(v >> 16);
  o.w = (float)(int8_t)(v >> 24);
  ((float4*)out)[(lo >> 2) + i] = o;
}

__global__ __launch_bounds__(256) void expand_head_k(const int8_t* __restrict__ st,
                                                     float* __restrict__ out) {
  uint32_t r[8];
  int t = threadIdx.x;
  for (int u = 0; u < 8; ++u) r[u] = *(const uint32_t*)(st + t * 32 + 4 * u);
  __syncthreads();
  for (int u = 0; u < 8; ++u) {
    uint32_t v = r[u];
    float4 o;
    o.x = (float)(int8_t)(v);
    o.y = (float)(int8_t)(v >> 8);
    o.z = (float)(int8_t)(v >> 16);
    o.w = (float)(int8_t)(v >> 24);
    ((float4*)out)[t * 8 + u] = o;
  }
}

extern "C" void kernel_launch(void* const* d_in, const int* in_sizes, int n_in,
                              void* d_out, int out_size, void* d_ws, size_t ws_size,
                              hipStream_t stream) {
  (void)in_sizes; (void)n_in; (void)out_size;
  const float* T    = (const float*)d_in[0];
  const int*  spins = (const int*)d_in[1];
  const int*  nsw   = (const int*)d_in[2];

  uint8_t* buf0 = (uint8_t*)d_out;
  float*   outf = (float*)d_out;
  float*   Eout = outf + NSITE;

  float*    Eplane = (float*)d_ws;               // 512 f
  uint32_t* M4     = (uint32_t*)(Eplane + 512);  // 32 u
  uint32_t* M8     = M4 + BB;                    // 32 u
  uint8_t*  wstate = (uint8_t*)d_ws + 4096;      // NSITE bytes (if room)
  bool big_ws = (ws_size >= (size_t)NSITE + 4096);

  init8_prep_k<<<NSITE / 1024, 256, 0, stream>>>(spins, buf0, T, M4, M8);

  uint32_t k3fa = 0, k3fb = 0;
  for (int g = 0; g < 4; ++g) {
    uint4 kS[4];
    uint32_t k3a = 0, k3b = 0;
    for (int i = 0; i < 4; ++i) {
      int t = 4 * g + i;
      uint32_t kb0, kb1;
      tf2x32(0u, 42u, 0u, (uint32_t)t, kb0, kb1);     // fold_in(key(42), t)
      tf2x32(kb0, kb1, 0u, 0u, kS[i].x, kS[i].y);     // color-0 key
      tf2x32(kb0, kb1, 0u, 1u, kS[i].z, kS[i].w);     // color-1 key
      if (i == 3) tf2x32(kb0, kb1, 0u, 2u, k3a, k3b); // PT key
    }
    sweep4_k<<<BB * CC, 1024, 0, stream>>>(buf0, M4, M8,
                                           kS[0], kS[1], kS[2], kS[3],
                                           4 * g, nsw, Eplane);
    if (g < 3) {
      pt_swapD_k<<<NPAIR, 256, 0, stream>>>(buf0, Eplane, T, k3a, k3b,
                                            g & 1, 4 * g + 3, nsw);
    } else {
      k3fa = k3a; k3fb = k3b;                        // t=15 PT key
    }
  }

  if (big_ws) {
    // t=15 swap applied as a permuting copy into ws; Eout written alongside.
    permute_out_k<<<BB * CC, 256, 0, stream>>>(buf0, wstate, Eplane, T,
                                               k3fa, k3fb, 1, 15, nsw, Eout);
    expand_full_k<<<NSITE / 1024, 256, 0, stream>>>(wstate, outf);
  } else {
    pt_swapD_k<<<NPAIR, 256, 0, stream>>>(buf0, Eplane, T, k3fa, k3fb,
                                          1, 15, nsw);
    final_eoutD_k<<<1, 512, 0, stream>>>(Eplane, T, k3fa, k3fb, 1, 15,
                                         nsw, Eout);
    for (int lo = NSITE / 4; lo >= 8192; lo >>= 2) {
      int cnt4 = (lo * 3) / 4;
      expand_k<<<(cnt4 + 255) / 256, 256, 0, stream>>>((int8_t*)buf0, outf,
                                                       lo, cnt4);
    }
    expand_head_k<<<1, 256, 0, stream>>>((int8_t*)buf0, outf);
  }
}

// Round 9
// 1415.704 us; speedup vs baseline: 1.2225x; 1.0272x over previous
//
#include <hip/hip_runtime.h>
#include <stdint.h>

// ---------------------------------------------------------------------------
// ThermalLatticeSampler2D — round 9: R6/R8 hot loop untouched (at int-VALU
// issue roofline: 4cyc/wave64 int op model confirmed by VALUBusy arithmetic).
// Tail collapsed: init fused into first sweep, thresholds computed in-block,
// state in d_ws, single fused permute+expand kernel. 8 launches (big-ws).
//
// Bit-exact jax.random (threefry2x32, partitionable mode) — validated R2-R8.
// ---------------------------------------------------------------------------

#define BB 32
#define CC 16
#define PLANE 65536
#define NSITE (BB * CC * PLANE)        // 33554432
#define NPAIR ((BB - 1) * CC)          // 496

// Full threefry (host key schedule + PT decisions).
__host__ __device__ __forceinline__ void tf2x32(uint32_t k0, uint32_t k1,
                                                uint32_t c0, uint32_t c1,
                                                uint32_t& o0, uint32_t& o1) {
  uint32_t ks2 = k0 ^ k1 ^ 0x1BD11BDAu;
  uint32_t x0 = c0 + k0;
  uint32_t x1 = c1 + k1;
#define TF_ROT(r) { x0 += x1; x1 = (x1 << (r)) | (x1 >> (32 - (r))); x1 ^= x0; }
  TF_ROT(13) TF_ROT(15) TF_ROT(26) TF_ROT(6)
  x0 += k1;  x1 += ks2 + 1u;
  TF_ROT(17) TF_ROT(29) TF_ROT(16) TF_ROT(24)
  x0 += ks2; x1 += k0 + 2u;
  TF_ROT(13) TF_ROT(15) TF_ROT(26) TF_ROT(6)
  x0 += k0;  x1 += k1 + 3u;
  TF_ROT(17) TF_ROT(29) TF_ROT(16) TF_ROT(24)
  x0 += k1;  x1 += ks2 + 4u;
  TF_ROT(13) TF_ROT(15) TF_ROT(26) TF_ROT(6)
  x0 += ks2; x1 += k0 + 5u;
#undef TF_ROT
  o0 = x0; o1 = x1;
}

// rotl pinned to 1-op v_alignbit_b32
__device__ __forceinline__ uint32_t rotl(uint32_t x, int r) {
  return __builtin_amdgcn_alignbit(x, x, 32 - r);
}

// Device hash, c0==0, x1i = c1 + k1 precomputed. Returns o0 ^ o1.
__device__ __forceinline__ uint32_t tf_bits(uint32_t k0, uint32_t k1,
                                            uint32_t ks2, uint32_t x1i) {
  uint32_t x0 = k0, x1 = x1i;
#define R4(a,b,c,d) \
  x0 += x1; x1 = rotl(x1, (a)); x1 ^= x0; \
  x0 += x1; x1 = rotl(x1, (b)); x1 ^= x0; \
  x0 += x1; x1 = rotl(x1, (c)); x1 ^= x0; \
  x0 += x1; x1 = rotl(x1, (d)); x1 ^= x0;
  R4(13,15,26,6)  x0 += k1;  x1 += ks2 + 1u;
  R4(17,29,16,24) x0 += ks2; x1 += k0 + 2u;
  R4(13,15,26,6)  x0 += k0;  x1 += k1 + 3u;
  R4(17,29,16,24) x0 += k1;  x1 += ks2 + 4u;
  R4(13,15,26,6)  x0 += ks2; x1 += k0 + 5u;
#undef R4
  return x0 ^ x1;
}

__device__ __forceinline__ float u01(uint32_t bits) {
  return __uint_as_float((bits >> 9) | 0x3f800000u) - 1.0f;
}

// Metropolis integer thresholds from T[b] (identical formula to R4-R8 prep_k).
__device__ __forceinline__ void mk_thresholds(float tb, uint32_t& M4b,
                                              uint32_t& M8b) {
  float th4 = (float)exp((double)((-4.0f) / tb));
  float th8 = (float)exp((double)((-8.0f) / tb));
  M4b = (uint32_t)ceil((double)th4 * 8388608.0);
  M8b = (uint32_t)ceil((double)th8 * 8388608.0);
}

// Shared PT pair-accept decision (identical math to validated pt_decide_k).
__device__ __forceinline__ bool pt_accept(int pair, const float* Eplane,
                                          const float* T,
                                          uint32_t k0, uint32_t k1) {
  int b = pair >> 4;
  float d = (1.0f / T[b] - 1.0f / T[b + 1])
          * (Eplane[pair] - Eplane[pair + 16]);
  uint32_t h0, h1;
  tf2x32(k0, k1, 0u, (uint32_t)pair, h0, h1);
  float u = u01(h0 ^ h1);
  float th = (float)exp((double)d);
  return u < th;
}

// ---- one color pass over the plane in LDS (R6/R8 verbatim — do not touch) --
__device__ __forceinline__ void do_color(uint32_t* __restrict__ tile,
    int w, int lane, int lm, int lp, uint32_t vk, int color,
    uint32_t k0, uint32_t k1, uint32_t ks2, uint32_t M4b, uint32_t M8b) {
#pragma unroll 4
  for (int it = 0; it < 16; ++it) {
    int j  = w + it * 16;                     // scalar
    int rb = j << 6;                          // scalar
    int ju = ((j + 255) & 255) << 6;          // scalar
    int jd = ((j + 1) & 255) << 6;            // scalar
    int p  = (j + color) & 1;                 // scalar
    uint32_t soff = (uint32_t)((j << 8) + p); // scalar

    uint32_t cur = tile[rb + lane];
    uint32_t up  = tile[ju + lane];
    uint32_t dn  = tile[jd + lane];
    uint32_t pw  = tile[rb + lm];
    uint32_t nw  = tile[rb + lp];
    uint32_t lft = __builtin_amdgcn_alignbit(cur, pw, 24);
    uint32_t rgt = __builtin_amdgcn_alignbit(nw, cur, 8);
    uint32_t kd2 = (up & 0x02020202u) + (dn & 0x02020202u)
                 + (lft & 0x02020202u) + (rgt & 0x02020202u);

    uint32_t flip = 0;
    {                                        // site A: byte p
      uint32_t kdi = (kd2 >> (8 * p)) & 0xFFu;
      uint32_t si  = (cur >> (8 * p + 1)) & 1u;
      uint32_t m2  = si ? (8u - kdi) : kdi;  // 2*(# antiparallel)
      bool a = true;                         // m2>=4 -> dE<=0 -> flip
      if (m2 < 4u) {
        uint32_t n = tf_bits(k0, k1, ks2, vk + soff) >> 9;
        a = n < (m2 == 2u ? M4b : M8b);
      }
      if (a) flip |= 0xFEu << (8 * p);
    }
    {                                        // site B: byte p+2
      uint32_t kdi = (kd2 >> (8 * p + 16)) & 0xFFu;
      uint32_t si  = (cur >> (8 * p + 17)) & 1u;
      uint32_t m2  = si ? (8u - kdi) : kdi;
      bool a = true;
      if (m2 < 4u) {
        uint32_t n = tf_bits(k0, k1, ks2, vk + soff + 2u) >> 9;
        a = n < (m2 == 2u ? M4b : M8b);
      }
      if (a) flip |= 0xFE0000u << (8 * p);
    }
    tile[rb + lane] = cur ^ flip;
  }
}

// ---- 4 sweeps on one plane, fully LDS-resident; exact energy at end -------
__global__ __launch_bounds__(1024) void sweep4_k(
    uint8_t* __restrict__ sg, const int* __restrict__ spins, int doInit,
    const float* __restrict__ T,
    uint4 kS0, uint4 kS1, uint4 kS2, uint4 kS3,
    int tbase, const int* __restrict__ nsw, float* __restrict__ Eplane) {
  __shared__ uint32_t tile[16384];           // exactly 64 KB
  int tid = threadIdx.x;
  int bc  = blockIdx.x;
  int b   = bc >> 4;
  uint32_t bcbase = (uint32_t)bc << 16;
  uint32_t* gp = (uint32_t*)(sg + ((size_t)bc << 16));
  uint32_t M4b, M8b;
  mk_thresholds(T[b], M4b, M8b);
  int nswv = *nsw;

  if (doInit) {                              // int32 {0,1} -> packed int8 +-1
    const int4* ip = (const int4*)(spins + ((size_t)bc << 16));
    for (int i = tid; i < 16384; i += 1024) {
      int4 v = ip[i];
      tile[i] = ((uint32_t)(uint8_t)(int8_t)(2 * v.x - 1))
              | ((uint32_t)(uint8_t)(int8_t)(2 * v.y - 1) << 8)
              | ((uint32_t)(uint8_t)(int8_t)(2 * v.z - 1) << 16)
              | ((uint32_t)(uint8_t)(int8_t)(2 * v.w - 1) << 24);
    }
  } else {
    for (int i = tid; i < 4096; i += 1024)
      ((uint4*)tile)[i] = ((const uint4*)gp)[i];
  }
  __syncthreads();

  int w    = __builtin_amdgcn_readfirstlane(tid >> 6);  // wave-uniform
  int lane = tid & 63;
  int lm   = (lane + 63) & 63, lp = (lane + 1) & 63;

  uint4 keys[4] = {kS0, kS1, kS2, kS3};
#pragma unroll
  for (int ss = 0; ss < 4; ++ss) {
    if (tbase + ss < nswv) {                 // uniform
      uint32_t kA0 = keys[ss].x, kA1 = keys[ss].y;
      uint32_t kB0 = keys[ss].z, kB1 = keys[ss].w;
      uint32_t ksA = kA0 ^ kA1 ^ 0x1BD11BDAu;
      uint32_t ksB = kB0 ^ kB1 ^ 0x1BD11BDAu;
      uint32_t vkA = kA1 + bcbase + (uint32_t)(lane << 2);
      uint32_t vkB = kB1 + bcbase + (uint32_t)(lane << 2);
      do_color(tile, w, lane, lm, lp, vkA, 0, kA0, kA1, ksA, M4b, M8b);
      __syncthreads();
      do_color(tile, w, lane, lm, lp, vkB, 1, kB0, kB1, ksB, M4b, M8b);
      __syncthreads();
    }
  }

  // exact integer energy partial: sum s*(right+down)
  int acc = 0;
  for (int it = 0; it < 16; ++it) {
    int j = w + it * 16;
    uint32_t cur = tile[(j << 6) + lane];
    uint32_t nxt = tile[(j << 6) + lp];
    uint32_t dwn = tile[((((j + 1) & 255)) << 6) + lane];
    uint32_t rsh = (cur >> 8) | (nxt << 24);
    int d = __builtin_popcount((cur ^ rsh) & 0x02020202u)
          + __builtin_popcount((cur ^ dwn) & 0x02020202u);
    acc += 8 - 2 * d;
  }

  for (int i = tid; i < 4096; i += 1024)
    ((uint4*)gp)[i] = ((uint4*)tile)[i];
  __syncthreads();

  for (int off = 32; off > 0; off >>= 1) acc += __shfl_down(acc, off, 64);
  if (lane == 0) tile[w] = (uint32_t)acc;
  __syncthreads();
  if (tid == 0) {
    int tot = 0;
    for (int i = 0; i < 16; ++i) tot += (int)tile[i];
    Eplane[bc] = -(float)tot;
  }
}

// ---- PT swap with inline decision -----------------------------------------
__global__ __launch_bounds__(256) void pt_swapD_k(uint8_t* __restrict__ s,
    const float* __restrict__ Eplane, const float* __restrict__ T,
    uint32_t k0, uint32_t k1, int pair_parity, int t,
    const int* __restrict__ nsw) {
  int pc = blockIdx.x;                       // pair index, 0..495
  int b  = pc >> 4;
  if ((b & 1) != pair_parity) return;
  if (t >= *nsw) return;
  if (!pt_accept(pc, Eplane, T, k0, k1)) return;
  uint4* p0 = (uint4*)(s + ((size_t)pc << 16));
  uint4* p1 = p0 + (CC * PLANE / 16);        // plane (b+1, c)
  for (int j = threadIdx.x; j < PLANE / 16; j += 256) {
    uint4 a0 = p0[j], a1 = p1[j];
    p0[j] = a1; p1[j] = a0;
  }
}

// ---- source plane after applying t=15 swap permutation --------------------
__device__ __forceinline__ int perm_src(int pc, const float* Eplane,
                                        const float* T, uint32_t k0,
                                        uint32_t k1, int pair_parity,
                                        int t, int nswv) {
  int b = pc >> 4;
  if (t < nswv) {
    if (b < 31 && (b & 1) == pair_parity &&
        pt_accept(pc, Eplane, T, k0, k1)) return pc + 16;
    if (b > 0 && ((b - 1) & 1) == pair_parity &&
        pt_accept(pc - 16, Eplane, T, k0, k1)) return pc - 16;
  }
  return pc;
}

// ---- main path: fused t=15 permute + int8->fp32 expand + Eout -------------
// State in ws (disjoint from d_out) -> direct expansion, no staging.
__global__ __launch_bounds__(256) void expand_perm_k(
    const uint8_t* __restrict__ s, float* __restrict__ out,
    const float* __restrict__ Eplane, const float* __restrict__ T,
    uint32_t k0, uint32_t k1, int pair_parity, int t,
    const int* __restrict__ nsw, float* __restrict__ Eout) {
  int pc  = blockIdx.x >> 3;                 // plane 0..511
  int sub = blockIdx.x & 7;                  // 1/8 of plane per block
  int src = perm_src(pc, Eplane, T, k0, k1, pair_parity, t, *nsw);
  const uint32_t* p0 = (const uint32_t*)(s + ((size_t)src << 16));
  float4* p1 = (float4*)(out + ((size_t)pc << 14));
  int base = sub * 2048;
  for (int j = threadIdx.x; j < 2048; j += 256) {
    uint32_t v = p0[base + j];
    float4 o;
    o.x = (float)(int8_t)(v);
    o.y = (float)(int8_t)(v >> 8);
    o.z = (float)(int8_t)(v >> 16);
    o.w = (float)(int8_t)(v >> 24);
    p1[base + j] = o;
  }
  if (threadIdx.x == 0 && sub == 0) Eout[pc] = Eplane[src];
}

// ---- fallback path (small ws): Eout + staged in-place expansion -----------
__global__ void final_eoutD_k(const float* __restrict__ Eplane,
                              const float* __restrict__ T,
                              uint32_t k0, uint32_t k1, int pair_parity,
                              int t, const int* __restrict__ nsw,
                              float* __restrict__ Eout) {
  int pc = threadIdx.x;                      // 512
  int src = perm_src(pc, Eplane, T, k0, k1, pair_parity, t, *nsw);
  Eout[pc] = Eplane[src];
}

__global__ __launch_bounds__(256) void expand_k(const int8_t* __restrict__ st,
                                                float* __restrict__ out,
                                                int lo, int cnt4) {
  int i = blockIdx.x * 256 + threadIdx.x;
  if (i >= cnt4) return;
  uint32_t v = *(const uint32_t*)(st + lo + 4 * i);
  float4 o;
  o.x = (float)(int8_t)(v);
  o.y = (float)(int8_t)(v >> 8);
  o.z = (float)(int8_t)(v >> 16);
  o.w = (float)(int8_t)(v >> 24);
  ((float4*)out)[(lo >> 2) + i] = o;
}

__global__ __launch_bounds__(256) void expand_head_k(const int8_t* __restrict__ st,
                                                     float* __restrict__ out) {
  uint32_t r[8];
  int t = threadIdx.x;
  for (int u = 0; u < 8; ++u) r[u] = *(const uint32_t*)(st + t * 32 + 4 * u);
  __syncthreads();
  for (int u = 0; u < 8; ++u) {
    uint32_t v = r[u];
    float4 o;
    o.x = (float)(int8_t)(v);
    o.y = (float)(int8_t)(v >> 8);
    o.z = (float)(int8_t)(v >> 16);
    o.w = (float)(int8_t)(v >> 24);
    ((float4*)out)[t * 8 + u] = o;
  }
}

extern "C" void kernel_launch(void* const* d_in, const int* in_sizes, int n_in,
                              void* d_out, int out_size, void* d_ws, size_t ws_size,
                              hipStream_t stream) {
  (void)in_sizes; (void)n_in; (void)out_size;
  const float* T    = (const float*)d_in[0];
  const int*  spins = (const int*)d_in[1];
  const int*  nsw   = (const int*)d_in[2];

  float* outf = (float*)d_out;
  float* Eout = outf + NSITE;

  float*   Eplane = (float*)d_ws;                // 512 f
  uint8_t* wstate = (uint8_t*)d_ws + 4096;       // NSITE bytes (if room)
  bool big_ws = (ws_size >= (size_t)NSITE + 4096);
  uint8_t* state = big_ws ? wstate : (uint8_t*)d_out;

  uint32_t k3fa = 0, k3fb = 0;
  for (int g = 0; g < 4; ++g) {
    uint4 kS[4];
    uint32_t k3a = 0, k3b = 0;
    for (int i = 0; i < 4; ++i) {
      int t = 4 * g + i;
      uint32_t kb0, kb1;
      tf2x32(0u, 42u, 0u, (uint32_t)t, kb0, kb1);     // fold_in(key(42), t)
      tf2x32(kb0, kb1, 0u, 0u, kS[i].x, kS[i].y);     // color-0 key
      tf2x32(kb0, kb1, 0u, 1u, kS[i].z, kS[i].w);     // color-1 key
      if (i == 3) tf2x32(kb0, kb1, 0u, 2u, k3a, k3b); // PT key
    }
    sweep4_k<<<BB * CC, 1024, 0, stream>>>(state, spins, (g == 0) ? 1 : 0,
                                           T, kS[0], kS[1], kS[2], kS[3],
                                           4 * g, nsw, Eplane);
    if (g < 3) {
      pt_swapD_k<<<NPAIR, 256, 0, stream>>>(state, Eplane, T, k3a, k3b,
                                            g & 1, 4 * g + 3, nsw);
    } else {
      k3fa = k3a; k3fb = k3b;                        // t=15 PT key
    }
  }

  if (big_ws) {
    expand_perm_k<<<BB * CC * 8, 256, 0, stream>>>(state, outf, Eplane, T,
                                                   k3fa, k3fb, 1, 15, nsw,
                                                   Eout);
  } else {
    pt_swapD_k<<<NPAIR, 256, 0, stream>>>(state, Eplane, T, k3fa, k3fb,
                                          1, 15, nsw);
    final_eoutD_k<<<1, 512, 0, stream>>>(Eplane, T, k3fa, k3fb, 1, 15,
                                         nsw, Eout);
    for (int lo = NSITE / 4; lo >= 8192; lo >>= 2) {
      int cnt4 = (lo * 3) / 4;
      expand_k<<<(cnt4 + 255) / 256, 256, 0, stream>>>((int8_t*)state, outf,
                                                       lo, cnt4);
    }
    expand_head_k<<<1, 256, 0, stream>>>((int8_t*)state, outf);
  }
}